// Round 16
// baseline (179.515 us; speedup 1.0000x reference)
//
#include <hip/hip_runtime.h>
#include <cstddef>

// CAM module, algebraically restructured:
//   X = concat(rgb,hsv,lab) : [B=4, 192, N=65536] (f32)
//   G[b] = X X^T (192x192 symmetric, upper block-triangle), s[b] = row sums
//   energy = (Wq G Wk^T + bq sk^T + sq bk^T + N bq bk^T)/8 ; att = softmax_d
//   M = att Wv (emitted as swizzled fp16) ; c0 = att bv   (K2, f32)
//   out = M X + c0                                  (K3, fp16 MFMA)
//
// R16: K1 rebuilt in K3's macro-shape (the one untested structural difference
// after 11 probes): 4-wave 256-thr blocks, 4/CU, independent short periods
// (de-phased load issue), half-triangle per block (acc[10]=40 AGPR as R11,
// unified ~100<=128). Paired halves share each 512-col window (2nd read is
// L3-served; X is L3-resident). All staging/swizzle/MFMA formulas = R11.

#define NPIX 65536

typedef _Float16 half4_t __attribute__((ext_vector_type(4)));
typedef _Float16 half8_t __attribute__((ext_vector_type(8)));
typedef float f32x4_t __attribute__((ext_vector_type(4)));

// upper block-triangle (I<=J) of the 12x12 tile grid, row-major: 78 tiles.
constexpr int TRI_I[78] = {
  0,0,0,0,0,0,0,0,0,0,0,0,
  1,1,1,1,1,1,1,1,1,1,1,
  2,2,2,2,2,2,2,2,2,2,
  3,3,3,3,3,3,3,3,3,
  4,4,4,4,4,4,4,4,
  5,5,5,5,5,5,5,
  6,6,6,6,6,6,
  7,7,7,7,7,
  8,8,8,8,
  9,9,9,
  10,10,
  11};
constexpr int TRI_J[78] = {
  0,1,2,3,4,5,6,7,8,9,10,11,
  1,2,3,4,5,6,7,8,9,10,11,
  2,3,4,5,6,7,8,9,10,11,
  3,4,5,6,7,8,9,10,11,
  4,5,6,7,8,9,10,11,
  5,6,7,8,9,10,11,
  6,7,8,9,10,11,
  7,8,9,10,11,
  8,9,10,11,
  9,10,11,
  10,11,
  11};

#define PSZ 20160  // per-slot partial: 78*256 triangle + 192 rowsums

// ---------------- K0: zero a float range ----------------
__global__ void k0_zero(float* __restrict__ p, int n) {
  int i = blockIdx.x * 256 + threadIdx.x;
  if (i < n) p[i] = 0.0f;
}

// ---- per-wave MFMA over a static contiguous triangle-tile run ----
template <int BASE, int CNT>
__device__ __forceinline__ void mfma_run(const _Float16* __restrict__ buf,
                                         f32x4_t* __restrict__ acc, int l15, int g) {
  half8_t fA;
#pragma unroll
  for (int tt = 0; tt < CNT; ++tt) {
    const int t = BASE + tt;           // compile-time after unroll
    if (tt == 0 || TRI_I[t] != TRI_I[t - 1]) {
      int rA = TRI_I[t] * 16 + l15;
      fA = *(const half8_t*)(buf + rA * 32 + ((g ^ ((rA >> 1) & 3)) << 3));
    }
    int rB = TRI_J[t] * 16 + l15;
    half8_t fB = *(const half8_t*)(buf + rB * 32 + ((g ^ ((rB >> 1) & 3)) << 3));
    acc[tt] = __builtin_amdgcn_mfma_f32_16x16x32_f16(fA, fB, acc[tt], 0, 0, 0);
  }
}

template <int BASE, int CNT>
__device__ __forceinline__ void flush_part(const f32x4_t* __restrict__ acc,
                                           float* __restrict__ pb, int lane) {
#pragma unroll
  for (int tt = 0; tt < CNT; ++tt)
    *(f32x4_t*)(pb + (BASE + tt) * 256 + lane * 4) = acc[tt];
}

template <int BASE, int CNT>
__device__ __forceinline__ void flush_atomic(const f32x4_t* __restrict__ acc,
                                             float* __restrict__ Gb, int lane) {
#pragma unroll
  for (int tt = 0; tt < CNT; ++tt) {
    const int t = BASE + tt;
#pragma unroll
    for (int r = 0; r < 4; ++r) {
      int gr = TRI_I[t] * 16 + ((lane >> 4) << 2) + r;
      int gc = TRI_J[t] * 16 + (lane & 15);
      atomicAdd(Gb + gr * 192 + gc, acc[tt][r]);
    }
  }
}

// ---------------- K1: Gram (half-triangle per block) + row sums ----------------
// grid (256, 4) = 1024 blocks (4/CU), block 256 (4 waves).
// blockIdx.x = {bx[0..127], half}: block does 512 cols, 16 chunks of 32 cols,
// computing triangle tiles [39*half, 39*half+39). Wave w: tiles base+w*10
// (w=3: 9 tiles). LDS: single [192][32] fp16 buffer (12 KB), R11's measured
// conflict-free layout. Loop: writeLDS; sync; load(next); compute; sync.
// Staging: thread t -> rows {r6, 64+r6, 128+r6} (r6=t>>2), granules 2q,2q+1
// (q=t&3) per row = 6 float4 loads. Rowsums from half-0 blocks only.
// mode: 1 = direct partials (128 slots/batch, halves share a slot with
// disjoint tile ranges), 0 = atomicAdd into zeroed G/S.
__global__ __launch_bounds__(256) void k1_gram(
    const float* __restrict__ rgb, const float* __restrict__ hsv, const float* __restrict__ lab,
    float* __restrict__ G, float* __restrict__ S, float* __restrict__ part, int mode) {
  __shared__ alignas(16) _Float16 lds[6144];  // 12 KB
  float* slds = (float*)lds;

  const int t = threadIdx.x;
  const int lane = t & 63;
  const int w = t >> 6;            // 0..3
  const int half = blockIdx.x & 1;
  const int bx = blockIdx.x >> 1;  // 0..127
  const int b = blockIdx.y;
  const int n0 = bx * 512;
  const int wsel = half * 4 + w;   // 0..7 tile-run selector

  const int q = t & 3;
  const int r6 = t >> 2;           // 0..63
  const float* gp0 = rgb + (size_t)(b * 64 + r6) * NPIX + n0 + 8 * q;
  const float* gp1 = hsv + (size_t)(b * 64 + r6) * NPIX + n0 + 8 * q;
  const float* gp2 = lab + (size_t)(b * 64 + r6) * NPIX + n0 + 8 * q;
  // R11 write formula with gq = 2q+j: wof = row*32 + ((q^sw)<<3) + j*4
  const int wb = ((q ^ ((r6 >> 1) & 3)) << 3);
  const int wof0 = (0 * 64 + r6) * 32 + wb;
  const int wof1 = (1 * 64 + r6) * 32 + wb;
  const int wof2 = (2 * 64 + r6) * 32 + wb;

  f32x4_t acc[10];
  const f32x4_t zero4 = {0.0f, 0.0f, 0.0f, 0.0f};
#pragma unroll
  for (int i = 0; i < 10; ++i) acc[i] = zero4;
  float sr0 = 0.f, sr1 = 0.f, sr2 = 0.f;

  float4 Pa0, Pb0, Pa1, Pb1, Pa2, Pb2;  // [source][granule j]
  auto loadR = [&](int cc) {
    Pa0 = *(const float4*)(gp0 + cc * 32);
    Pb0 = *(const float4*)(gp0 + cc * 32 + 4);
    Pa1 = *(const float4*)(gp1 + cc * 32);
    Pb1 = *(const float4*)(gp1 + cc * 32 + 4);
    Pa2 = *(const float4*)(gp2 + cc * 32);
    Pb2 = *(const float4*)(gp2 + cc * 32 + 4);
  };
  auto writeL = [&]() {
    half4_t h;
    sr0 += (Pa0.x + Pa0.y) + (Pa0.z + Pa0.w) + (Pb0.x + Pb0.y) + (Pb0.z + Pb0.w);
    h.x = (_Float16)Pa0.x; h.y = (_Float16)Pa0.y; h.z = (_Float16)Pa0.z; h.w = (_Float16)Pa0.w;
    *(half4_t*)(lds + wof0) = h;
    h.x = (_Float16)Pb0.x; h.y = (_Float16)Pb0.y; h.z = (_Float16)Pb0.z; h.w = (_Float16)Pb0.w;
    *(half4_t*)(lds + wof0 + 4) = h;
    sr1 += (Pa1.x + Pa1.y) + (Pa1.z + Pa1.w) + (Pb1.x + Pb1.y) + (Pb1.z + Pb1.w);
    h.x = (_Float16)Pa1.x; h.y = (_Float16)Pa1.y; h.z = (_Float16)Pa1.z; h.w = (_Float16)Pa1.w;
    *(half4_t*)(lds + wof1) = h;
    h.x = (_Float16)Pb1.x; h.y = (_Float16)Pb1.y; h.z = (_Float16)Pb1.z; h.w = (_Float16)Pb1.w;
    *(half4_t*)(lds + wof1 + 4) = h;
    sr2 += (Pa2.x + Pa2.y) + (Pa2.z + Pa2.w) + (Pb2.x + Pb2.y) + (Pb2.z + Pb2.w);
    h.x = (_Float16)Pa2.x; h.y = (_Float16)Pa2.y; h.z = (_Float16)Pa2.z; h.w = (_Float16)Pa2.w;
    *(half4_t*)(lds + wof2) = h;
    h.x = (_Float16)Pb2.x; h.y = (_Float16)Pb2.y; h.z = (_Float16)Pb2.z; h.w = (_Float16)Pb2.w;
    *(half4_t*)(lds + wof2 + 4) = h;
  };

  const int l15 = lane & 15;
  const int g = lane >> 4;

  loadR(0);
  for (int cc = 0; cc < 16; ++cc) {
    writeL();                        // waits on P (loads from prev iteration)
    __syncthreads();
    if (cc + 1 < 16) loadR(cc + 1);  // in flight under compute
    switch (wsel) {
      case 0: mfma_run<0, 10>(lds, acc, l15, g); break;
      case 1: mfma_run<10, 10>(lds, acc, l15, g); break;
      case 2: mfma_run<20, 10>(lds, acc, l15, g); break;
      case 3: mfma_run<30, 9>(lds, acc, l15, g); break;
      case 4: mfma_run<39, 10>(lds, acc, l15, g); break;
      case 5: mfma_run<49, 10>(lds, acc, l15, g); break;
      case 6: mfma_run<59, 10>(lds, acc, l15, g); break;
      case 7: mfma_run<69, 9>(lds, acc, l15, g); break;
    }
    __syncthreads();
  }

  // ---- flush Gram (this block's 39 triangle tiles across 4 waves) ----
  if (mode) {
    float* pb = part + (size_t)(b * 128 + bx) * PSZ;
    switch (wsel) {
      case 0: flush_part<0, 10>(acc, pb, lane); break;
      case 1: flush_part<10, 10>(acc, pb, lane); break;
      case 2: flush_part<20, 10>(acc, pb, lane); break;
      case 3: flush_part<30, 9>(acc, pb, lane); break;
      case 4: flush_part<39, 10>(acc, pb, lane); break;
      case 5: flush_part<49, 10>(acc, pb, lane); break;
      case 6: flush_part<59, 10>(acc, pb, lane); break;
      case 7: flush_part<69, 9>(acc, pb, lane); break;
    }
  } else {
    float* Gb = G + b * 36864;
    switch (wsel) {
      case 0: flush_atomic<0, 10>(acc, Gb, lane); break;
      case 1: flush_atomic<10, 10>(acc, Gb, lane); break;
      case 2: flush_atomic<20, 10>(acc, Gb, lane); break;
      case 3: flush_atomic<30, 9>(acc, Gb, lane); break;
      case 4: flush_atomic<39, 10>(acc, Gb, lane); break;
      case 5: flush_atomic<49, 10>(acc, Gb, lane); break;
      case 6: flush_atomic<59, 10>(acc, Gb, lane); break;
      case 7: flush_atomic<69, 9>(acc, Gb, lane); break;
    }
  }

  // ---- row sums: half-0 blocks only (they staged all 192 rows) ----
  if (half == 0) {
    slds[(0 * 64 + r6) * 4 + q] = sr0;
    slds[(1 * 64 + r6) * 4 + q] = sr1;
    slds[(2 * 64 + r6) * 4 + q] = sr2;
    __syncthreads();
    if (t < 192) {
      float v = (slds[4 * t] + slds[4 * t + 1]) + (slds[4 * t + 2] + slds[4 * t + 3]);
      if (mode)
        part[(size_t)(b * 128 + bx) * PSZ + 19968 + t] = v;
      else
        atomicAdd(S + b * 192 + t, v);
    }
  }
}

// ---------------- K1.5a: deterministic reduce of 128 partials + mirror ----------------
__global__ void k1r_reduce(const float* __restrict__ part, float* __restrict__ G,
                           float* __restrict__ S) {
  int idx = blockIdx.x * 256 + threadIdx.x;
  if (idx >= 4 * (PSZ / 4)) return;
  int b = idx / (PSZ / 4);
  int f4 = idx % (PSZ / 4);
  int flat = f4 * 4;
  const float* base = part + (size_t)b * 128 * PSZ + flat;
  f32x4_t v0 = {0.f, 0.f, 0.f, 0.f}, v1 = v0, v2 = v0, v3 = v0;
#pragma unroll 4
  for (int q = 0; q < 128; q += 4) {
    v0 += *(const f32x4_t*)(base + (size_t)(q + 0) * PSZ);
    v1 += *(const f32x4_t*)(base + (size_t)(q + 1) * PSZ);
    v2 += *(const f32x4_t*)(base + (size_t)(q + 2) * PSZ);
    v3 += *(const f32x4_t*)(base + (size_t)(q + 3) * PSZ);
  }
  f32x4_t v = (v0 + v1) + (v2 + v3);
  if (flat < 19968) {
    int tt = flat >> 8;
    int r = flat & 255;          // divisible by 4
    int lane = r >> 2;
    int row = TRI_I[tt] * 16 + ((lane >> 4) << 2);  // + rg for component rg
    int col = TRI_J[tt] * 16 + (lane & 15);
    float* Gb = G + b * 36864;
#pragma unroll
    for (int e = 0; e < 4; ++e) Gb[(row + e) * 192 + col] = v[e];
    *(f32x4_t*)(Gb + col * 192 + row) = v;  // mirror, contiguous (diag benign)
  } else {
    *(f32x4_t*)(S + b * 192 + (flat - 19968)) = v;
  }
}

// ---------------- K1.5b (atomic fallback): mirror lower block-triangle ----------------
__global__ void k1m_mirror(float* __restrict__ G) {
  int b = blockIdx.y;
  int idx = blockIdx.x * 256 + threadIdx.x;
  int i = idx / 192, j = idx % 192;
  if ((i >> 4) > (j >> 4)) G[b * 36864 + idx] = G[b * 36864 + j * 192 + i];
}

// ---------------- K2: energy -> softmax -> M(fp16 swizzled), c0 ----------------
__global__ __launch_bounds__(256) void k2_small(
    const float* __restrict__ G, const float* __restrict__ S,
    const float* __restrict__ Wq, const float* __restrict__ bq,
    const float* __restrict__ Wk, const float* __restrict__ bk,
    const float* __restrict__ Wv, const float* __restrict__ bv,
    _Float16* __restrict__ Mh, float* __restrict__ c0w) {
  const int b = blockIdx.y;
  const int cbase = blockIdx.x * 8;
  const int t = threadIdx.x;
  __shared__ float T1[192 * 9];
  __shared__ float el[64 * 8];
  __shared__ float sq[8];
  __shared__ float sk[64];
  const float* Gb = G + b * 36864;
  const float* Sb = S + b * 192;

  if (t < 8) {
    float a = 0.f;
    const float* wq = Wq + (cbase + t) * 192;
    for (int i = 0; i < 192; ++i) a = fmaf(wq[i], Sb[i], a);
    sq[t] = a;
  } else if (t < 72) {
    int d = t - 8;
    float a = 0.f;
    const float* wk = Wk + d * 192;
    for (int j = 0; j < 192; ++j) a = fmaf(wk[j], Sb[j], a);
    sk[d] = a;
  }
  for (int e = t; e < 1536; e += 256) {
    int j = e % 192, cp = e / 192;
    const float* wq = Wq + (cbase + cp) * 192;
    float a = 0.f;
    for (int i = 0; i < 192; ++i) a = fmaf(wq[i], Gb[i * 192 + j], a);
    T1[j * 9 + cp] = a;
  }
  __syncthreads();
  for (int e = t; e < 512; e += 256) {
    int cp = e & 7, d = e >> 3;
    const float* wk = Wk + d * 192;
    float a = 0.f;
    for (int j = 0; j < 192; ++j) a = fmaf(T1[j * 9 + cp], wk[j], a);
    float bqc = bq[cbase + cp], bkd = bk[d];
    a += bqc * sk[d] + bkd * sq[cp] + 65536.0f * bqc * bkd;
    el[d * 8 + cp] = a * 0.125f;
  }
  __syncthreads();
  if (t < 8) {
    float mx = -3.0e38f;
    for (int d = 0; d < 64; ++d) mx = fmaxf(mx, el[d * 8 + t]);
    float sum = 0.f;
    for (int d = 0; d < 64; ++d) {
      float pv = expf(el[d * 8 + t] - mx);
      el[d * 8 + t] = pv;
      sum += pv;
    }
    float inv = 1.0f / sum;
    for (int d = 0; d < 64; ++d) el[d * 8 + t] *= inv;
  }
  __syncthreads();
  // M rows in fp16, swizzled exactly as K3's lds_m image: idx = c*192 + (i ^ ((c&7)<<3))
  for (int e = t; e < 1536; e += 256) {
    int i = e % 192, cp = e / 192;
    int c = cbase + cp;
    float a = 0.f;
    for (int d = 0; d < 64; ++d) a = fmaf(el[d * 8 + cp], Wv[d * 192 + i], a);
    Mh[(size_t)b * 12288 + c * 192 + (i ^ ((c & 7) << 3))] = (_Float16)a;
  }
  if (t < 8) {
    float a = 0.f;
    for (int d = 0; d < 64; ++d) a = fmaf(el[d * 8 + t], bv[d], a);
    c0w[b * 64 + cbase + t] = a;
  }
}

// ---------------- K3: out = M X + c0 (fp16 MFMA) ----------------
// grid (256, 4), block 256 (4 waves). Block: C[64 x 256n]; wave w: n-span w*64.
// X chunk [32 i][256 n] staged transposed into lds_x[n][32] fp16, swizzle i^=(n&3)<<3.
// M staged once (linear copy of pre-swizzled fp16 image). acc[4][4] = 64 VGPR.
__global__ __launch_bounds__(256, 3) void k3_out(
    const float* __restrict__ rgb, const float* __restrict__ hsv, const float* __restrict__ lab,
    const _Float16* __restrict__ Mh, const float* __restrict__ c0w, float* __restrict__ out) {
  __shared__ alignas(16) _Float16 lds_m[12288];
  __shared__ alignas(16) _Float16 lds_x[8192];
  __shared__ float c0l[64];
  const int t = threadIdx.x;
  const int lane = t & 63;
  const int w = t >> 6;
  const int b = blockIdx.y;
  const int nblk = blockIdx.x * 256;

  {  // stage M (24576 B) as 16B copies + c0
    const float4* msrc = (const float4*)(Mh + (size_t)b * 12288);
    float4* mdst = (float4*)lds_m;
#pragma unroll
    for (int k = 0; k < 6; ++k) mdst[t + 256 * k] = msrc[t + 256 * k];
    if (t < 64) c0l[t] = c0w[b * 64 + t];
  }

  const int xi = t & 31;   // i within chunk
  const int ng = t >> 5;   // 0..7: n-group of 32
  const float* srcs[3] = {rgb, hsv, lab};

  f32x4_t acc[4][4];
  const f32x4_t zero4 = {0.0f, 0.0f, 0.0f, 0.0f};
#pragma unroll
  for (int i = 0; i < 4; ++i)
#pragma unroll
    for (int j = 0; j < 4; ++j) acc[i][j] = zero4;

  float4 xr[8];
  auto xload = [&](int kc) {
    int ig = kc * 32 + xi;
    const float* p = srcs[ig >> 6] + (size_t)(b * 64 + (ig & 63)) * NPIX + nblk + ng * 32;
#pragma unroll
    for (int f = 0; f < 8; ++f) xr[f] = *(const float4*)(p + f * 4);
  };
  auto xwrite = [&]() {
#pragma unroll
    for (int f = 0; f < 8; ++f) {
      int n = ng * 32 + f * 4;
      lds_x[(n + 0) * 32 + (xi ^ 0)]  = (_Float16)xr[f].x;
      lds_x[(n + 1) * 32 + (xi ^ 8)]  = (_Float16)xr[f].y;
      lds_x[(n + 2) * 32 + (xi ^ 16)] = (_Float16)xr[f].z;
      lds_x[(n + 3) * 32 + (xi ^ 24)] = (_Float16)xr[f].w;
    }
  };

  const int g = lane >> 4;     // 0..3
  const int l15 = lane & 15;

  xload(0);
  for (int kc = 0; kc < 6; ++kc) {
    xwrite();
    __syncthreads();
    if (kc + 1 < 6) xload(kc + 1);
    half8_t fx[4], fm[4];
#pragma unroll
    for (int nt = 0; nt < 4; ++nt) {
      int n = w * 64 + nt * 16 + l15;
      fx[nt] = *(const half8_t*)(lds_x + n * 32 + ((8 * g) ^ ((n & 3) << 3)));
    }
#pragma unroll
    for (int ct = 0; ct < 4; ++ct) {
      int c = ct * 16 + l15;
      fm[ct] = *(const half8_t*)(lds_m + c * 192 + ((kc * 32 + 8 * g) ^ ((c & 7) << 3)));
    }
#pragma unroll
    for (int nt = 0; nt < 4; ++nt)
#pragma unroll
      for (int ct = 0; ct < 4; ++ct)
        acc[nt][ct] = __builtin_amdgcn_mfma_f32_16x16x32_f16(fx[nt], fm[ct], acc[nt][ct], 0, 0, 0);
    __syncthreads();
  }

  // epilogue: C-row (n) = 4*g + r from first operand, C-col (c) = l15 from second
#pragma unroll
  for (int ct = 0; ct < 4; ++ct) {
    int c = ct * 16 + l15;
    float c0v = c0l[c];
#pragma unroll
    for (int nt = 0; nt < 4; ++nt) {
      int n = nblk + w * 64 + nt * 16 + 4 * g;
      float4 o;
      o.x = acc[nt][ct][0] + c0v;
      o.y = acc[nt][ct][1] + c0v;
      o.z = acc[nt][ct][2] + c0v;
      o.w = acc[nt][ct][3] + c0v;
      *(float4*)(out + (size_t)(b * 64 + c) * NPIX + n) = o;
    }
  }
}

extern "C" void kernel_launch(void* const* d_in, const int* in_sizes, int n_in,
                              void* d_out, int out_size, void* d_ws, size_t ws_size,
                              hipStream_t stream) {
  const float* rgb = (const float*)d_in[0];
  const float* hsv = (const float*)d_in[1];
  const float* lab = (const float*)d_in[2];
  const float* Wq = (const float*)d_in[3];
  const float* bq = (const float*)d_in[4];
  const float* Wk = (const float*)d_in[5];
  const float* bk = (const float*)d_in[6];
  const float* Wv = (const float*)d_in[7];
  const float* bv = (const float*)d_in[8];
  float* out = (float*)d_out;
  float* ws = (float*)d_ws;

  float* G = ws;                            // 147456 f32
  float* S = ws + 147456;                   // 768
  _Float16* Mh = (_Float16*)(ws + 148224);  // 49152 halves = 24576 f32 slots
  float* c0w = ws + 172800;                 // 256
  float* part = ws + 173056;                // 4*128*PSZ f32 = 41.3 MB
  const size_t need1 = (size_t)(173056 + 4 * 128 * PSZ) * 4;  // ~42 MB
  const int mode = ws_size >= need1 ? 1 : 0;

  if (!mode)
    k0_zero<<<dim3(579), dim3(256), 0, stream>>>(ws, 148224);  // zero G + S

  k1_gram<<<dim3(256, 4), dim3(256), 0, stream>>>(rgb, hsv, lab, G, S, part, mode);
  if (mode)
    k1r_reduce<<<dim3(79), dim3(256), 0, stream>>>(part, G, S);
  else
    k1m_mirror<<<dim3(144, 4), dim3(256), 0, stream>>>(G);
  k2_small<<<dim3(8, 4), dim3(256), 0, stream>>>(G, S, Wq, bq, Wk, bk, Wv, bv, Mh, c0w);
  k3_out<<<dim3(256, 4), dim3(256), 0, stream>>>(rgb, hsv, lab, Mh, c0w, out);
}

// Round 17
// 157.652 us; speedup vs baseline: 1.1387x; 1.1387x over previous
//
#include <hip/hip_runtime.h>
#include <cstddef>

// CAM module, algebraically restructured:
//   X = concat(rgb,hsv,lab) : [B=4, 192, N=65536] (f32)
//   G[b] = X X^T (192x192 symmetric, upper block-triangle), s[b] = row sums
//   energy = (Wq G Wk^T + bq sk^T + sq bk^T + N bq bk^T)/8 ; att = softmax_d
//   M = att Wv (emitted as swizzled fp16) ; c0 = att bv   (K2, f32)
//   out = M X + c0                                  (K3, fp16 MFMA)
//
// R16 finding: 4-wave small blocks sustained 3.0 TB/s (vs 1.7 max for all
// 8-12-wave variants) but duplicated reads (FETCH 196 MB) ate the gain.
// R17: same macro-shape, READ-ONCE - each 4-wave block owns an exclusive
// 512-col window and computes the FULL 78-tile triangle (20/20/20/18 per
// wave, acc[20] = 80 AGPR; unified ~172 -> 2 blocks/CU, still >=2
// independent de-phased domains). All staging/swizzle/MFMA formulas = R11.

#define NPIX 65536

typedef _Float16 half4_t __attribute__((ext_vector_type(4)));
typedef _Float16 half8_t __attribute__((ext_vector_type(8)));
typedef float f32x4_t __attribute__((ext_vector_type(4)));

// upper block-triangle (I<=J) of the 12x12 tile grid, row-major: 78 tiles.
constexpr int TRI_I[78] = {
  0,0,0,0,0,0,0,0,0,0,0,0,
  1,1,1,1,1,1,1,1,1,1,1,
  2,2,2,2,2,2,2,2,2,2,
  3,3,3,3,3,3,3,3,3,
  4,4,4,4,4,4,4,4,
  5,5,5,5,5,5,5,
  6,6,6,6,6,6,
  7,7,7,7,7,
  8,8,8,8,
  9,9,9,
  10,10,
  11};
constexpr int TRI_J[78] = {
  0,1,2,3,4,5,6,7,8,9,10,11,
  1,2,3,4,5,6,7,8,9,10,11,
  2,3,4,5,6,7,8,9,10,11,
  3,4,5,6,7,8,9,10,11,
  4,5,6,7,8,9,10,11,
  5,6,7,8,9,10,11,
  6,7,8,9,10,11,
  7,8,9,10,11,
  8,9,10,11,
  9,10,11,
  10,11,
  11};

#define PSZ 20160  // per-slot partial: 78*256 triangle + 192 rowsums

// ---------------- K0: zero a float range ----------------
__global__ void k0_zero(float* __restrict__ p, int n) {
  int i = blockIdx.x * 256 + threadIdx.x;
  if (i < n) p[i] = 0.0f;
}

// ---- per-wave MFMA over a static contiguous triangle-tile run ----
template <int BASE, int CNT>
__device__ __forceinline__ void mfma_run(const _Float16* __restrict__ buf,
                                         f32x4_t* __restrict__ acc, int l15, int g) {
  half8_t fA;
#pragma unroll
  for (int tt = 0; tt < CNT; ++tt) {
    const int t = BASE + tt;           // compile-time after unroll
    if (tt == 0 || TRI_I[t] != TRI_I[t - 1]) {
      int rA = TRI_I[t] * 16 + l15;
      fA = *(const half8_t*)(buf + rA * 32 + ((g ^ ((rA >> 1) & 3)) << 3));
    }
    int rB = TRI_J[t] * 16 + l15;
    half8_t fB = *(const half8_t*)(buf + rB * 32 + ((g ^ ((rB >> 1) & 3)) << 3));
    acc[tt] = __builtin_amdgcn_mfma_f32_16x16x32_f16(fA, fB, acc[tt], 0, 0, 0);
  }
}

template <int BASE, int CNT>
__device__ __forceinline__ void flush_part(const f32x4_t* __restrict__ acc,
                                           float* __restrict__ pb, int lane) {
#pragma unroll
  for (int tt = 0; tt < CNT; ++tt)
    *(f32x4_t*)(pb + (BASE + tt) * 256 + lane * 4) = acc[tt];
}

template <int BASE, int CNT>
__device__ __forceinline__ void flush_atomic(const f32x4_t* __restrict__ acc,
                                             float* __restrict__ Gb, int lane) {
#pragma unroll
  for (int tt = 0; tt < CNT; ++tt) {
    const int t = BASE + tt;
#pragma unroll
    for (int r = 0; r < 4; ++r) {
      int gr = TRI_I[t] * 16 + ((lane >> 4) << 2) + r;
      int gc = TRI_J[t] * 16 + (lane & 15);
      atomicAdd(Gb + gr * 192 + gc, acc[tt][r]);
    }
  }
}

// ---------------- K1: Gram (full triangle per block) + row sums ----------------
// grid (128, 4) = 512 blocks, block 256 (4 waves). Block owns an exclusive
// 512-col window (read-once), 16 chunks of 32 cols. Wave w: triangle-tile
// runs 20/20/20/18; acc[20] = 80 AGPR. LDS: single [192][32] fp16 buffer
// (12 KB), R11's measured conflict-free layout.
// Loop: writeLDS; sync; load(next); compute; sync.
// Staging: thread t -> rows {r6, 64+r6, 128+r6} (r6=t>>2), granules 2q,2q+1
// (q=t&3) per row = 6 float4 loads.
// mode: 1 = direct partials (128 slots/batch), 0 = atomicAdd into zeroed G/S.
__global__ __launch_bounds__(256) void k1_gram(
    const float* __restrict__ rgb, const float* __restrict__ hsv, const float* __restrict__ lab,
    float* __restrict__ G, float* __restrict__ S, float* __restrict__ part, int mode) {
  __shared__ alignas(16) _Float16 lds[6144];  // 12 KB
  float* slds = (float*)lds;

  const int t = threadIdx.x;
  const int lane = t & 63;
  const int w = t >> 6;            // 0..3
  const int bx = blockIdx.x;       // 0..127
  const int b = blockIdx.y;
  const int n0 = bx * 512;

  const int q = t & 3;
  const int r6 = t >> 2;           // 0..63
  const float* gp0 = rgb + (size_t)(b * 64 + r6) * NPIX + n0 + 8 * q;
  const float* gp1 = hsv + (size_t)(b * 64 + r6) * NPIX + n0 + 8 * q;
  const float* gp2 = lab + (size_t)(b * 64 + r6) * NPIX + n0 + 8 * q;
  // R11 write formula with gq = 2q+j: wof = row*32 + ((q^sw)<<3) + j*4
  const int wb = ((q ^ ((r6 >> 1) & 3)) << 3);
  const int wof0 = (0 * 64 + r6) * 32 + wb;
  const int wof1 = (1 * 64 + r6) * 32 + wb;
  const int wof2 = (2 * 64 + r6) * 32 + wb;

  f32x4_t acc[20];
  const f32x4_t zero4 = {0.0f, 0.0f, 0.0f, 0.0f};
#pragma unroll
  for (int i = 0; i < 20; ++i) acc[i] = zero4;
  float sr0 = 0.f, sr1 = 0.f, sr2 = 0.f;

  float4 Pa0, Pb0, Pa1, Pb1, Pa2, Pb2;  // [source][granule j]
  auto loadR = [&](int cc) {
    Pa0 = *(const float4*)(gp0 + cc * 32);
    Pb0 = *(const float4*)(gp0 + cc * 32 + 4);
    Pa1 = *(const float4*)(gp1 + cc * 32);
    Pb1 = *(const float4*)(gp1 + cc * 32 + 4);
    Pa2 = *(const float4*)(gp2 + cc * 32);
    Pb2 = *(const float4*)(gp2 + cc * 32 + 4);
  };
  auto writeL = [&]() {
    half4_t h;
    sr0 += (Pa0.x + Pa0.y) + (Pa0.z + Pa0.w) + (Pb0.x + Pb0.y) + (Pb0.z + Pb0.w);
    h.x = (_Float16)Pa0.x; h.y = (_Float16)Pa0.y; h.z = (_Float16)Pa0.z; h.w = (_Float16)Pa0.w;
    *(half4_t*)(lds + wof0) = h;
    h.x = (_Float16)Pb0.x; h.y = (_Float16)Pb0.y; h.z = (_Float16)Pb0.z; h.w = (_Float16)Pb0.w;
    *(half4_t*)(lds + wof0 + 4) = h;
    sr1 += (Pa1.x + Pa1.y) + (Pa1.z + Pa1.w) + (Pb1.x + Pb1.y) + (Pb1.z + Pb1.w);
    h.x = (_Float16)Pa1.x; h.y = (_Float16)Pa1.y; h.z = (_Float16)Pa1.z; h.w = (_Float16)Pa1.w;
    *(half4_t*)(lds + wof1) = h;
    h.x = (_Float16)Pb1.x; h.y = (_Float16)Pb1.y; h.z = (_Float16)Pb1.z; h.w = (_Float16)Pb1.w;
    *(half4_t*)(lds + wof1 + 4) = h;
    sr2 += (Pa2.x + Pa2.y) + (Pa2.z + Pa2.w) + (Pb2.x + Pb2.y) + (Pb2.z + Pb2.w);
    h.x = (_Float16)Pa2.x; h.y = (_Float16)Pa2.y; h.z = (_Float16)Pa2.z; h.w = (_Float16)Pa2.w;
    *(half4_t*)(lds + wof2) = h;
    h.x = (_Float16)Pb2.x; h.y = (_Float16)Pb2.y; h.z = (_Float16)Pb2.z; h.w = (_Float16)Pb2.w;
    *(half4_t*)(lds + wof2 + 4) = h;
  };

  const int l15 = lane & 15;
  const int g = lane >> 4;

  loadR(0);
  for (int cc = 0; cc < 16; ++cc) {
    writeL();                        // waits on P (loads from prev iteration)
    __syncthreads();
    if (cc + 1 < 16) loadR(cc + 1);  // in flight under compute
    switch (w) {
      case 0: mfma_run<0, 20>(lds, acc, l15, g); break;
      case 1: mfma_run<20, 20>(lds, acc, l15, g); break;
      case 2: mfma_run<40, 20>(lds, acc, l15, g); break;
      case 3: mfma_run<60, 18>(lds, acc, l15, g); break;
    }
    __syncthreads();
  }

  // ---- flush Gram (this block's full 78 triangle tiles across 4 waves) ----
  if (mode) {
    float* pb = part + (size_t)(b * 128 + bx) * PSZ;
    switch (w) {
      case 0: flush_part<0, 20>(acc, pb, lane); break;
      case 1: flush_part<20, 20>(acc, pb, lane); break;
      case 2: flush_part<40, 20>(acc, pb, lane); break;
      case 3: flush_part<60, 18>(acc, pb, lane); break;
    }
  } else {
    float* Gb = G + b * 36864;
    switch (w) {
      case 0: flush_atomic<0, 20>(acc, Gb, lane); break;
      case 1: flush_atomic<20, 20>(acc, Gb, lane); break;
      case 2: flush_atomic<40, 20>(acc, Gb, lane); break;
      case 3: flush_atomic<60, 18>(acc, Gb, lane); break;
    }
  }

  // ---- row sums (every block; exclusive window) ----
  slds[(0 * 64 + r6) * 4 + q] = sr0;
  slds[(1 * 64 + r6) * 4 + q] = sr1;
  slds[(2 * 64 + r6) * 4 + q] = sr2;
  __syncthreads();
  if (t < 192) {
    float v = (slds[4 * t] + slds[4 * t + 1]) + (slds[4 * t + 2] + slds[4 * t + 3]);
    if (mode)
      part[(size_t)(b * 128 + bx) * PSZ + 19968 + t] = v;
    else
      atomicAdd(S + b * 192 + t, v);
  }
}

// ---------------- K1.5a: deterministic reduce of 128 partials + mirror ----------------
__global__ void k1r_reduce(const float* __restrict__ part, float* __restrict__ G,
                           float* __restrict__ S) {
  int idx = blockIdx.x * 256 + threadIdx.x;
  if (idx >= 4 * (PSZ / 4)) return;
  int b = idx / (PSZ / 4);
  int f4 = idx % (PSZ / 4);
  int flat = f4 * 4;
  const float* base = part + (size_t)b * 128 * PSZ + flat;
  f32x4_t v0 = {0.f, 0.f, 0.f, 0.f}, v1 = v0, v2 = v0, v3 = v0;
#pragma unroll 4
  for (int q = 0; q < 128; q += 4) {
    v0 += *(const f32x4_t*)(base + (size_t)(q + 0) * PSZ);
    v1 += *(const f32x4_t*)(base + (size_t)(q + 1) * PSZ);
    v2 += *(const f32x4_t*)(base + (size_t)(q + 2) * PSZ);
    v3 += *(const f32x4_t*)(base + (size_t)(q + 3) * PSZ);
  }
  f32x4_t v = (v0 + v1) + (v2 + v3);
  if (flat < 19968) {
    int tt = flat >> 8;
    int r = flat & 255;          // divisible by 4
    int lane = r >> 2;
    int row = TRI_I[tt] * 16 + ((lane >> 4) << 2);  // + rg for component rg
    int col = TRI_J[tt] * 16 + (lane & 15);
    float* Gb = G + b * 36864;
#pragma unroll
    for (int e = 0; e < 4; ++e) Gb[(row + e) * 192 + col] = v[e];
    *(f32x4_t*)(Gb + col * 192 + row) = v;  // mirror, contiguous (diag benign)
  } else {
    *(f32x4_t*)(S + b * 192 + (flat - 19968)) = v;
  }
}

// ---------------- K1.5b (atomic fallback): mirror lower block-triangle ----------------
__global__ void k1m_mirror(float* __restrict__ G) {
  int b = blockIdx.y;
  int idx = blockIdx.x * 256 + threadIdx.x;
  int i = idx / 192, j = idx % 192;
  if ((i >> 4) > (j >> 4)) G[b * 36864 + idx] = G[b * 36864 + j * 192 + i];
}

// ---------------- K2: energy -> softmax -> M(fp16 swizzled), c0 ----------------
__global__ __launch_bounds__(256) void k2_small(
    const float* __restrict__ G, const float* __restrict__ S,
    const float* __restrict__ Wq, const float* __restrict__ bq,
    const float* __restrict__ Wk, const float* __restrict__ bk,
    const float* __restrict__ Wv, const float* __restrict__ bv,
    _Float16* __restrict__ Mh, float* __restrict__ c0w) {
  const int b = blockIdx.y;
  const int cbase = blockIdx.x * 8;
  const int t = threadIdx.x;
  __shared__ float T1[192 * 9];
  __shared__ float el[64 * 8];
  __shared__ float sq[8];
  __shared__ float sk[64];
  const float* Gb = G + b * 36864;
  const float* Sb = S + b * 192;

  if (t < 8) {
    float a = 0.f;
    const float* wq = Wq + (cbase + t) * 192;
    for (int i = 0; i < 192; ++i) a = fmaf(wq[i], Sb[i], a);
    sq[t] = a;
  } else if (t < 72) {
    int d = t - 8;
    float a = 0.f;
    const float* wk = Wk + d * 192;
    for (int j = 0; j < 192; ++j) a = fmaf(wk[j], Sb[j], a);
    sk[d] = a;
  }
  for (int e = t; e < 1536; e += 256) {
    int j = e % 192, cp = e / 192;
    const float* wq = Wq + (cbase + cp) * 192;
    float a = 0.f;
    for (int i = 0; i < 192; ++i) a = fmaf(wq[i], Gb[i * 192 + j], a);
    T1[j * 9 + cp] = a;
  }
  __syncthreads();
  for (int e = t; e < 512; e += 256) {
    int cp = e & 7, d = e >> 3;
    const float* wk = Wk + d * 192;
    float a = 0.f;
    for (int j = 0; j < 192; ++j) a = fmaf(T1[j * 9 + cp], wk[j], a);
    float bqc = bq[cbase + cp], bkd = bk[d];
    a += bqc * sk[d] + bkd * sq[cp] + 65536.0f * bqc * bkd;
    el[d * 8 + cp] = a * 0.125f;
  }
  __syncthreads();
  if (t < 8) {
    float mx = -3.0e38f;
    for (int d = 0; d < 64; ++d) mx = fmaxf(mx, el[d * 8 + t]);
    float sum = 0.f;
    for (int d = 0; d < 64; ++d) {
      float pv = expf(el[d * 8 + t] - mx);
      el[d * 8 + t] = pv;
      sum += pv;
    }
    float inv = 1.0f / sum;
    for (int d = 0; d < 64; ++d) el[d * 8 + t] *= inv;
  }
  __syncthreads();
  // M rows in fp16, swizzled exactly as K3's lds_m image: idx = c*192 + (i ^ ((c&7)<<3))
  for (int e = t; e < 1536; e += 256) {
    int i = e % 192, cp = e / 192;
    int c = cbase + cp;
    float a = 0.f;
    for (int d = 0; d < 64; ++d) a = fmaf(el[d * 8 + cp], Wv[d * 192 + i], a);
    Mh[(size_t)b * 12288 + c * 192 + (i ^ ((c & 7) << 3))] = (_Float16)a;
  }
  if (t < 8) {
    float a = 0.f;
    for (int d = 0; d < 64; ++d) a = fmaf(el[d * 8 + t], bv[d], a);
    c0w[b * 64 + cbase + t] = a;
  }
}

// ---------------- K3: out = M X + c0 (fp16 MFMA) ----------------
// grid (256, 4), block 256 (4 waves). Block: C[64 x 256n]; wave w: n-span w*64.
// X chunk [32 i][256 n] staged transposed into lds_x[n][32] fp16, swizzle i^=(n&3)<<3.
// M staged once (linear copy of pre-swizzled fp16 image). acc[4][4] = 64 VGPR.
__global__ __launch_bounds__(256, 3) void k3_out(
    const float* __restrict__ rgb, const float* __restrict__ hsv, const float* __restrict__ lab,
    const _Float16* __restrict__ Mh, const float* __restrict__ c0w, float* __restrict__ out) {
  __shared__ alignas(16) _Float16 lds_m[12288];
  __shared__ alignas(16) _Float16 lds_x[8192];
  __shared__ float c0l[64];
  const int t = threadIdx.x;
  const int lane = t & 63;
  const int w = t >> 6;
  const int b = blockIdx.y;
  const int nblk = blockIdx.x * 256;

  {  // stage M (24576 B) as 16B copies + c0
    const float4* msrc = (const float4*)(Mh + (size_t)b * 12288);
    float4* mdst = (float4*)lds_m;
#pragma unroll
    for (int k = 0; k < 6; ++k) mdst[t + 256 * k] = msrc[t + 256 * k];
    if (t < 64) c0l[t] = c0w[b * 64 + t];
  }

  const int xi = t & 31;   // i within chunk
  const int ng = t >> 5;   // 0..7: n-group of 32
  const float* srcs[3] = {rgb, hsv, lab};

  f32x4_t acc[4][4];
  const f32x4_t zero4 = {0.0f, 0.0f, 0.0f, 0.0f};
#pragma unroll
  for (int i = 0; i < 4; ++i)
#pragma unroll
    for (int j = 0; j < 4; ++j) acc[i][j] = zero4;

  float4 xr[8];
  auto xload = [&](int kc) {
    int ig = kc * 32 + xi;
    const float* p = srcs[ig >> 6] + (size_t)(b * 64 + (ig & 63)) * NPIX + nblk + ng * 32;
#pragma unroll
    for (int f = 0; f < 8; ++f) xr[f] = *(const float4*)(p + f * 4);
  };
  auto xwrite = [&]() {
#pragma unroll
    for (int f = 0; f < 8; ++f) {
      int n = ng * 32 + f * 4;
      lds_x[(n + 0) * 32 + (xi ^ 0)]  = (_Float16)xr[f].x;
      lds_x[(n + 1) * 32 + (xi ^ 8)]  = (_Float16)xr[f].y;
      lds_x[(n + 2) * 32 + (xi ^ 16)] = (_Float16)xr[f].z;
      lds_x[(n + 3) * 32 + (xi ^ 24)] = (_Float16)xr[f].w;
    }
  };

  const int g = lane >> 4;     // 0..3
  const int l15 = lane & 15;

  xload(0);
  for (int kc = 0; kc < 6; ++kc) {
    xwrite();
    __syncthreads();
    if (kc + 1 < 6) xload(kc + 1);
    half8_t fx[4], fm[4];
#pragma unroll
    for (int nt = 0; nt < 4; ++nt) {
      int n = w * 64 + nt * 16 + l15;
      fx[nt] = *(const half8_t*)(lds_x + n * 32 + ((8 * g) ^ ((n & 3) << 3)));
    }
#pragma unroll
    for (int ct = 0; ct < 4; ++ct) {
      int c = ct * 16 + l15;
      fm[ct] = *(const half8_t*)(lds_m + c * 192 + ((kc * 32 + 8 * g) ^ ((c & 7) << 3)));
    }
#pragma unroll
    for (int nt = 0; nt < 4; ++nt)
#pragma unroll
      for (int ct = 0; ct < 4; ++ct)
        acc[nt][ct] = __builtin_amdgcn_mfma_f32_16x16x32_f16(fx[nt], fm[ct], acc[nt][ct], 0, 0, 0);
    __syncthreads();
  }

  // epilogue: C-row (n) = 4*g + r from first operand, C-col (c) = l15 from second
#pragma unroll
  for (int ct = 0; ct < 4; ++ct) {
    int c = ct * 16 + l15;
    float c0v = c0l[c];
#pragma unroll
    for (int nt = 0; nt < 4; ++nt) {
      int n = nblk + w * 64 + nt * 16 + 4 * g;
      float4 o;
      o.x = acc[nt][ct][0] + c0v;
      o.y = acc[nt][ct][1] + c0v;
      o.z = acc[nt][ct][2] + c0v;
      o.w = acc[nt][ct][3] + c0v;
      *(float4*)(out + (size_t)(b * 64 + c) * NPIX + n) = o;
    }
  }
}

extern "C" void kernel_launch(void* const* d_in, const int* in_sizes, int n_in,
                              void* d_out, int out_size, void* d_ws, size_t ws_size,
                              hipStream_t stream) {
  const float* rgb = (const float*)d_in[0];
  const float* hsv = (const float*)d_in[1];
  const float* lab = (const float*)d_in[2];
  const float* Wq = (const float*)d_in[3];
  const float* bq = (const float*)d_in[4];
  const float* Wk = (const float*)d_in[5];
  const float* bk = (const float*)d_in[6];
  const float* Wv = (const float*)d_in[7];
  const float* bv = (const float*)d_in[8];
  float* out = (float*)d_out;
  float* ws = (float*)d_ws;

  float* G = ws;                            // 147456 f32
  float* S = ws + 147456;                   // 768
  _Float16* Mh = (_Float16*)(ws + 148224);  // 49152 halves = 24576 f32 slots
  float* c0w = ws + 172800;                 // 256
  float* part = ws + 173056;                // 4*128*PSZ f32 = 41.3 MB
  const size_t need1 = (size_t)(173056 + 4 * 128 * PSZ) * 4;  // ~42 MB
  const int mode = ws_size >= need1 ? 1 : 0;

  if (!mode)
    k0_zero<<<dim3(579), dim3(256), 0, stream>>>(ws, 148224);  // zero G + S

  k1_gram<<<dim3(128, 4), dim3(256), 0, stream>>>(rgb, hsv, lab, G, S, part, mode);
  if (mode)
    k1r_reduce<<<dim3(79), dim3(256), 0, stream>>>(part, G, S);
  else
    k1m_mirror<<<dim3(144, 4), dim3(256), 0, stream>>>(G);
  k2_small<<<dim3(8, 4), dim3(256), 0, stream>>>(G, S, Wq, bq, Wk, bk, Wv, bv, Mh, c0w);
  k3_out<<<dim3(256, 4), dim3(256), 0, stream>>>(rgb, hsv, lab, Mh, c0w, out);
}

// Round 18
// 149.089 us; speedup vs baseline: 1.2041x; 1.0574x over previous
//
#include <hip/hip_runtime.h>
#include <cstddef>

// CAM module, algebraically restructured (SESSION-BEST CONFIGURATION = R11).
//   X = concat(rgb,hsv,lab) : [B=4, 192, N=65536] (f32)
//   G[b] = X X^T (192x192 symmetric, upper block-triangle), s[b] = row sums
//   energy = (Wq G Wk^T + bq sk^T + sq bk^T + N bq bk^T)/8 ; att = softmax_d
//   M = att Wv (emitted as swizzled fp16) ; c0 = att bv   (K2, f32)
//   out = M X + c0                                  (K3, fp16 MFMA)
//
// Session summary (17 rounds): 570 -> 147.7 us. K1 (Gram) is pinned at
// ~82-95 us across FOURTEEN structures (reg-staged / DMA / fp16-LDS /
// counted-vmcnt depth-3 / 1-2-4 blocks/CU / wide windows / phase rotation /
// read-once small blocks). Characterization: ~2.5 us unhidden load latency
// per chunk-period per block; co-residency divides it but register pressure
// (acc + staging vs the 64/128/256 VGPR occupancy quantum) caps co-residency
// at 2-3 for triangle-covering accumulators. K3 is near its memory roofline.

#define NPIX 65536

typedef _Float16 half4_t __attribute__((ext_vector_type(4)));
typedef _Float16 half8_t __attribute__((ext_vector_type(8)));
typedef float f32x4_t __attribute__((ext_vector_type(4)));

// upper block-triangle (I<=J) of the 12x12 tile grid, row-major: 78 tiles.
constexpr int TRI_I[78] = {
  0,0,0,0,0,0,0,0,0,0,0,0,
  1,1,1,1,1,1,1,1,1,1,1,
  2,2,2,2,2,2,2,2,2,2,
  3,3,3,3,3,3,3,3,3,
  4,4,4,4,4,4,4,4,
  5,5,5,5,5,5,5,
  6,6,6,6,6,6,
  7,7,7,7,7,
  8,8,8,8,
  9,9,9,
  10,10,
  11};
constexpr int TRI_J[78] = {
  0,1,2,3,4,5,6,7,8,9,10,11,
  1,2,3,4,5,6,7,8,9,10,11,
  2,3,4,5,6,7,8,9,10,11,
  3,4,5,6,7,8,9,10,11,
  4,5,6,7,8,9,10,11,
  5,6,7,8,9,10,11,
  6,7,8,9,10,11,
  7,8,9,10,11,
  8,9,10,11,
  9,10,11,
  10,11,
  11};

#define PSZ 20160  // per-slot partial: 78*256 triangle + 192 rowsums

// ---------------- K0: zero a float range ----------------
__global__ void k0_zero(float* __restrict__ p, int n) {
  int i = blockIdx.x * 256 + threadIdx.x;
  if (i < n) p[i] = 0.0f;
}

// ---- per-wave MFMA over a static contiguous triangle-tile run ----
template <int BASE, int CNT>
__device__ __forceinline__ void mfma_run(const _Float16* __restrict__ buf,
                                         f32x4_t* __restrict__ acc, int l15, int g) {
  half8_t fA;
#pragma unroll
  for (int tt = 0; tt < CNT; ++tt) {
    const int t = BASE + tt;           // compile-time after unroll
    if (tt == 0 || TRI_I[t] != TRI_I[t - 1]) {
      int rA = TRI_I[t] * 16 + l15;
      fA = *(const half8_t*)(buf + rA * 32 + ((g ^ ((rA >> 1) & 3)) << 3));
    }
    int rB = TRI_J[t] * 16 + l15;
    half8_t fB = *(const half8_t*)(buf + rB * 32 + ((g ^ ((rB >> 1) & 3)) << 3));
    acc[tt] = __builtin_amdgcn_mfma_f32_16x16x32_f16(fA, fB, acc[tt], 0, 0, 0);
  }
}

template <int BASE, int CNT>
__device__ __forceinline__ void flush_part(const f32x4_t* __restrict__ acc,
                                           float* __restrict__ pb, int lane) {
#pragma unroll
  for (int tt = 0; tt < CNT; ++tt)
    *(f32x4_t*)(pb + (BASE + tt) * 256 + lane * 4) = acc[tt];
}

template <int BASE, int CNT>
__device__ __forceinline__ void flush_atomic(const f32x4_t* __restrict__ acc,
                                             float* __restrict__ Gb, int lane) {
#pragma unroll
  for (int tt = 0; tt < CNT; ++tt) {
    const int t = BASE + tt;
#pragma unroll
    for (int r = 0; r < 4; ++r) {
      int gr = TRI_I[t] * 16 + ((lane >> 4) << 2) + r;
      int gc = TRI_J[t] * 16 + (lane & 15);
      atomicAdd(Gb + gr * 192 + gc, acc[tt][r]);
    }
  }
}

// ---------------- K1: Gram (triangle) + row sums ----------------
// grid (128, 4) = 512 blocks, block 512 (8 waves). 512 cols/block, 16 chunks
// of 32 cols. LDS: single [192][32] fp16 buffer (12 KB), measured
// conflict-free layout: halves granule G at row*32 + ((G^((row>>1)&3))<<3).
// Loop: writeLDS; sync; load(next); compute; sync.
// Wave w owns triangle tiles [w*10, w*10+10) (wave 7: 8). acc <= 40 regs.
// mode: 1 = direct partials (128 slots/batch), 0 = atomicAdd into zeroed G/S.
__global__ __launch_bounds__(512) void k1_gram(
    const float* __restrict__ rgb, const float* __restrict__ hsv, const float* __restrict__ lab,
    float* __restrict__ G, float* __restrict__ S, float* __restrict__ part, int mode) {
  __shared__ alignas(16) _Float16 lds[6144];  // 12 KB
  float* slds = (float*)lds;

  const int t = threadIdx.x;
  const int lane = t & 63;
  const int w = t >> 6;           // 0..7
  const int b = blockIdx.y;
  const int bx = blockIdx.x;      // 0..127
  const int n0 = bx * 512;

  // staging map: thread -> granule gq = t&7 (4 f32), base row r6 = t>>3 (0..63);
  // covers rows {r6, 64+r6, 128+r6} from rgb/hsv/lab respectively.
  const int gq = t & 7;
  const int r6 = t >> 3;
  const float* gp0 = rgb + (size_t)(b * 64 + r6) * NPIX + n0 + 4 * gq;
  const float* gp1 = hsv + (size_t)(b * 64 + r6) * NPIX + n0 + 4 * gq;
  const float* gp2 = lab + (size_t)(b * 64 + r6) * NPIX + n0 + 4 * gq;
  // write offset: swizzle depends on (row>>1)&3 = (r6>>1)&3 (row=rep*64+r6)
  const int wsw = (((gq >> 1) ^ ((r6 >> 1) & 3)) << 3) + (gq & 1) * 4;
  const int wof0 = (0 * 64 + r6) * 32 + wsw;
  const int wof1 = (1 * 64 + r6) * 32 + wsw;
  const int wof2 = (2 * 64 + r6) * 32 + wsw;

  f32x4_t acc[10];
  const f32x4_t zero4 = {0.0f, 0.0f, 0.0f, 0.0f};
#pragma unroll
  for (int i = 0; i < 10; ++i) acc[i] = zero4;
  float sr0 = 0.f, sr1 = 0.f, sr2 = 0.f;

  float4 P0, P1, P2;
  auto loadR = [&](int cc) {
    P0 = *(const float4*)(gp0 + cc * 32);
    P1 = *(const float4*)(gp1 + cc * 32);
    P2 = *(const float4*)(gp2 + cc * 32);
  };
  auto writeL = [&]() {
    half4_t h;
    sr0 += (P0.x + P0.y) + (P0.z + P0.w);
    h.x = (_Float16)P0.x; h.y = (_Float16)P0.y; h.z = (_Float16)P0.z; h.w = (_Float16)P0.w;
    *(half4_t*)(lds + wof0) = h;
    sr1 += (P1.x + P1.y) + (P1.z + P1.w);
    h.x = (_Float16)P1.x; h.y = (_Float16)P1.y; h.z = (_Float16)P1.z; h.w = (_Float16)P1.w;
    *(half4_t*)(lds + wof1) = h;
    sr2 += (P2.x + P2.y) + (P2.z + P2.w);
    h.x = (_Float16)P2.x; h.y = (_Float16)P2.y; h.z = (_Float16)P2.z; h.w = (_Float16)P2.w;
    *(half4_t*)(lds + wof2) = h;
  };

  const int l15 = lane & 15;
  const int g = lane >> 4;

  loadR(0);
  for (int cc = 0; cc < 16; ++cc) {
    writeL();                        // waits on P (loads from prev iteration)
    __syncthreads();
    if (cc + 1 < 16) loadR(cc + 1);  // in flight under compute
    switch (w) {
      case 0: mfma_run<0, 10>(lds, acc, l15, g); break;
      case 1: mfma_run<10, 10>(lds, acc, l15, g); break;
      case 2: mfma_run<20, 10>(lds, acc, l15, g); break;
      case 3: mfma_run<30, 10>(lds, acc, l15, g); break;
      case 4: mfma_run<40, 10>(lds, acc, l15, g); break;
      case 5: mfma_run<50, 10>(lds, acc, l15, g); break;
      case 6: mfma_run<60, 10>(lds, acc, l15, g); break;
      case 7: mfma_run<70, 8>(lds, acc, l15, g); break;
    }
    __syncthreads();
  }

  // ---- flush Gram (this block's 78 triangle tiles across 8 waves) ----
  if (mode) {
    float* pb = part + (size_t)(b * 128 + bx) * PSZ;
    switch (w) {
      case 0: flush_part<0, 10>(acc, pb, lane); break;
      case 1: flush_part<10, 10>(acc, pb, lane); break;
      case 2: flush_part<20, 10>(acc, pb, lane); break;
      case 3: flush_part<30, 10>(acc, pb, lane); break;
      case 4: flush_part<40, 10>(acc, pb, lane); break;
      case 5: flush_part<50, 10>(acc, pb, lane); break;
      case 6: flush_part<60, 10>(acc, pb, lane); break;
      case 7: flush_part<70, 8>(acc, pb, lane); break;
    }
  } else {
    float* Gb = G + b * 36864;
    switch (w) {
      case 0: flush_atomic<0, 10>(acc, Gb, lane); break;
      case 1: flush_atomic<10, 10>(acc, Gb, lane); break;
      case 2: flush_atomic<20, 10>(acc, Gb, lane); break;
      case 3: flush_atomic<30, 10>(acc, Gb, lane); break;
      case 4: flush_atomic<40, 10>(acc, Gb, lane); break;
      case 5: flush_atomic<50, 10>(acc, Gb, lane); break;
      case 6: flush_atomic<60, 10>(acc, Gb, lane); break;
      case 7: flush_atomic<70, 8>(acc, Gb, lane); break;
    }
  }

  // ---- row sums: reuse LDS as f32 scratch (compute fully done after loop) ----
  slds[(0 * 64 + r6) * 8 + gq] = sr0;
  slds[(1 * 64 + r6) * 8 + gq] = sr1;
  slds[(2 * 64 + r6) * 8 + gq] = sr2;
  __syncthreads();
  if (t < 192) {
    float v = 0.f;
#pragma unroll
    for (int q = 0; q < 8; ++q) v += slds[t * 8 + q];
    if (mode)
      part[(size_t)(b * 128 + bx) * PSZ + 19968 + t] = v;
    else
      atomicAdd(S + b * 192 + t, v);
  }
}

// ---------------- K1.5a: deterministic reduce of 128 partials + mirror ----------------
__global__ void k1r_reduce(const float* __restrict__ part, float* __restrict__ G,
                           float* __restrict__ S) {
  int idx = blockIdx.x * 256 + threadIdx.x;
  if (idx >= 4 * PSZ) return;
  int b = idx / PSZ;
  int flat = idx % PSZ;
  const float* base = part + (size_t)b * 128 * PSZ + flat;
  float v0 = 0.f, v1 = 0.f, v2 = 0.f, v3 = 0.f;
#pragma unroll 4
  for (int q = 0; q < 128; q += 4) {
    v0 += base[(size_t)(q + 0) * PSZ];
    v1 += base[(size_t)(q + 1) * PSZ];
    v2 += base[(size_t)(q + 2) * PSZ];
    v3 += base[(size_t)(q + 3) * PSZ];
  }
  float v = (v0 + v1) + (v2 + v3);
  if (flat < 19968) {
    int tt = flat >> 8;
    int r = flat & 255;
    int lane = r >> 2, rg = r & 3;
    int row = TRI_I[tt] * 16 + ((lane >> 4) << 2) + rg;
    int col = TRI_J[tt] * 16 + (lane & 15);
    float* Gb = G + b * 36864;
    Gb[row * 192 + col] = v;
    Gb[col * 192 + row] = v;  // mirror (diagonal tiles: benign double-write)
  } else {
    S[b * 192 + (flat - 19968)] = v;
  }
}

// ---------------- K1.5b (atomic fallback): mirror lower block-triangle ----------------
__global__ void k1m_mirror(float* __restrict__ G) {
  int b = blockIdx.y;
  int idx = blockIdx.x * 256 + threadIdx.x;
  int i = idx / 192, j = idx % 192;
  if ((i >> 4) > (j >> 4)) G[b * 36864 + idx] = G[b * 36864 + j * 192 + i];
}

// ---------------- K2: energy -> softmax -> M(fp16 swizzled), c0 ----------------
__global__ __launch_bounds__(256) void k2_small(
    const float* __restrict__ G, const float* __restrict__ S,
    const float* __restrict__ Wq, const float* __restrict__ bq,
    const float* __restrict__ Wk, const float* __restrict__ bk,
    const float* __restrict__ Wv, const float* __restrict__ bv,
    _Float16* __restrict__ Mh, float* __restrict__ c0w) {
  const int b = blockIdx.y;
  const int cbase = blockIdx.x * 8;
  const int t = threadIdx.x;
  __shared__ float T1[192 * 9];
  __shared__ float el[64 * 8];
  __shared__ float sq[8];
  __shared__ float sk[64];
  const float* Gb = G + b * 36864;
  const float* Sb = S + b * 192;

  if (t < 8) {
    float a = 0.f;
    const float* wq = Wq + (cbase + t) * 192;
    for (int i = 0; i < 192; ++i) a = fmaf(wq[i], Sb[i], a);
    sq[t] = a;
  } else if (t < 72) {
    int d = t - 8;
    float a = 0.f;
    const float* wk = Wk + d * 192;
    for (int j = 0; j < 192; ++j) a = fmaf(wk[j], Sb[j], a);
    sk[d] = a;
  }
  for (int e = t; e < 1536; e += 256) {
    int j = e % 192, cp = e / 192;
    const float* wq = Wq + (cbase + cp) * 192;
    float a = 0.f;
    for (int i = 0; i < 192; ++i) a = fmaf(wq[i], Gb[i * 192 + j], a);
    T1[j * 9 + cp] = a;
  }
  __syncthreads();
  for (int e = t; e < 512; e += 256) {
    int cp = e & 7, d = e >> 3;
    const float* wk = Wk + d * 192;
    float a = 0.f;
    for (int j = 0; j < 192; ++j) a = fmaf(T1[j * 9 + cp], wk[j], a);
    float bqc = bq[cbase + cp], bkd = bk[d];
    a += bqc * sk[d] + bkd * sq[cp] + 65536.0f * bqc * bkd;
    el[d * 8 + cp] = a * 0.125f;
  }
  __syncthreads();
  if (t < 8) {
    float mx = -3.0e38f;
    for (int d = 0; d < 64; ++d) mx = fmaxf(mx, el[d * 8 + t]);
    float sum = 0.f;
    for (int d = 0; d < 64; ++d) {
      float pv = expf(el[d * 8 + t] - mx);
      el[d * 8 + t] = pv;
      sum += pv;
    }
    float inv = 1.0f / sum;
    for (int d = 0; d < 64; ++d) el[d * 8 + t] *= inv;
  }
  __syncthreads();
  // M rows in fp16, swizzled exactly as K3's lds_m image: idx = c*192 + (i ^ ((c&7)<<3))
  for (int e = t; e < 1536; e += 256) {
    int i = e % 192, cp = e / 192;
    int c = cbase + cp;
    float a = 0.f;
    for (int d = 0; d < 64; ++d) a = fmaf(el[d * 8 + cp], Wv[d * 192 + i], a);
    Mh[(size_t)b * 12288 + c * 192 + (i ^ ((c & 7) << 3))] = (_Float16)a;
  }
  if (t < 8) {
    float a = 0.f;
    for (int d = 0; d < 64; ++d) a = fmaf(el[d * 8 + t], bv[d], a);
    c0w[b * 64 + cbase + t] = a;
  }
}

// ---------------- K3: out = M X + c0 (fp16 MFMA) ----------------
// grid (256, 4), block 256 (4 waves). Block: C[64 x 256n]; wave w: n-span w*64.
// X chunk [32 i][256 n] staged transposed into lds_x[n][32] fp16, swizzle i^=(n&3)<<3.
// M staged once (linear copy of pre-swizzled fp16 image). acc[4][4] = 64 VGPR.
__global__ __launch_bounds__(256, 3) void k3_out(
    const float* __restrict__ rgb, const float* __restrict__ hsv, const float* __restrict__ lab,
    const _Float16* __restrict__ Mh, const float* __restrict__ c0w, float* __restrict__ out) {
  __shared__ alignas(16) _Float16 lds_m[12288];
  __shared__ alignas(16) _Float16 lds_x[8192];
  __shared__ float c0l[64];
  const int t = threadIdx.x;
  const int lane = t & 63;
  const int w = t >> 6;
  const int b = blockIdx.y;
  const int nblk = blockIdx.x * 256;

  {  // stage M (24576 B) as 16B copies + c0
    const float4* msrc = (const float4*)(Mh + (size_t)b * 12288);
    float4* mdst = (float4*)lds_m;
#pragma unroll
    for (int k = 0; k < 6; ++k) mdst[t + 256 * k] = msrc[t + 256 * k];
    if (t < 64) c0l[t] = c0w[b * 64 + t];
  }

  const int xi = t & 31;   // i within chunk
  const int ng = t >> 5;   // 0..7: n-group of 32
  const float* srcs[3] = {rgb, hsv, lab};

  f32x4_t acc[4][4];
  const f32x4_t zero4 = {0.0f, 0.0f, 0.0f, 0.0f};
#pragma unroll
  for (int i = 0; i < 4; ++i)
#pragma unroll
    for (int j = 0; j < 4; ++j) acc[i][j] = zero4;

  float4 xr[8];
  auto xload = [&](int kc) {
    int ig = kc * 32 + xi;
    const float* p = srcs[ig >> 6] + (size_t)(b * 64 + (ig & 63)) * NPIX + nblk + ng * 32;
#pragma unroll
    for (int f = 0; f < 8; ++f) xr[f] = *(const float4*)(p + f * 4);
  };
  auto xwrite = [&]() {
#pragma unroll
    for (int f = 0; f < 8; ++f) {
      int n = ng * 32 + f * 4;
      lds_x[(n + 0) * 32 + (xi ^ 0)]  = (_Float16)xr[f].x;
      lds_x[(n + 1) * 32 + (xi ^ 8)]  = (_Float16)xr[f].y;
      lds_x[(n + 2) * 32 + (xi ^ 16)] = (_Float16)xr[f].z;
      lds_x[(n + 3) * 32 + (xi ^ 24)] = (_Float16)xr[f].w;
    }
  };

  const int g = lane >> 4;     // 0..3
  const int l15 = lane & 15;

  xload(0);
  for (int kc = 0; kc < 6; ++kc) {
    xwrite();
    __syncthreads();
    if (kc + 1 < 6) xload(kc + 1);
    half8_t fx[4], fm[4];
#pragma unroll
    for (int nt = 0; nt < 4; ++nt) {
      int n = w * 64 + nt * 16 + l15;
      fx[nt] = *(const half8_t*)(lds_x + n * 32 + ((8 * g) ^ ((n & 3) << 3)));
    }
#pragma unroll
    for (int ct = 0; ct < 4; ++ct) {
      int c = ct * 16 + l15;
      fm[ct] = *(const half8_t*)(lds_m + c * 192 + ((kc * 32 + 8 * g) ^ ((c & 7) << 3)));
    }
#pragma unroll
    for (int nt = 0; nt < 4; ++nt)
#pragma unroll
      for (int ct = 0; ct < 4; ++ct)
        acc[nt][ct] = __builtin_amdgcn_mfma_f32_16x16x32_f16(fx[nt], fm[ct], acc[nt][ct], 0, 0, 0);
    __syncthreads();
  }

  // epilogue: C-row (n) = 4*g + r from first operand, C-col (c) = l15 from second
#pragma unroll
  for (int ct = 0; ct < 4; ++ct) {
    int c = ct * 16 + l15;
    float c0v = c0l[c];
#pragma unroll
    for (int nt = 0; nt < 4; ++nt) {
      int n = nblk + w * 64 + nt * 16 + 4 * g;
      float4 o;
      o.x = acc[nt][ct][0] + c0v;
      o.y = acc[nt][ct][1] + c0v;
      o.z = acc[nt][ct][2] + c0v;
      o.w = acc[nt][ct][3] + c0v;
      *(float4*)(out + (size_t)(b * 64 + c) * NPIX + n) = o;
    }
  }
}

extern "C" void kernel_launch(void* const* d_in, const int* in_sizes, int n_in,
                              void* d_out, int out_size, void* d_ws, size_t ws_size,
                              hipStream_t stream) {
  const float* rgb = (const float*)d_in[0];
  const float* hsv = (const float*)d_in[1];
  const float* lab = (const float*)d_in[2];
  const float* Wq = (const float*)d_in[3];
  const float* bq = (const float*)d_in[4];
  const float* Wk = (const float*)d_in[5];
  const float* bk = (const float*)d_in[6];
  const float* Wv = (const float*)d_in[7];
  const float* bv = (const float*)d_in[8];
  float* out = (float*)d_out;
  float* ws = (float*)d_ws;

  float* G = ws;                            // 147456 f32
  float* S = ws + 147456;                   // 768
  _Float16* Mh = (_Float16*)(ws + 148224);  // 49152 halves = 24576 f32 slots
  float* c0w = ws + 172800;                 // 256
  float* part = ws + 173056;                // 4*128*PSZ f32 = 41.3 MB
  const size_t need1 = (size_t)(173056 + 4 * 128 * PSZ) * 4;  // ~42 MB
  const int mode = ws_size >= need1 ? 1 : 0;

  if (!mode)
    k0_zero<<<dim3(579), dim3(256), 0, stream>>>(ws, 148224);  // zero G + S

  k1_gram<<<dim3(128, 4), dim3(512), 0, stream>>>(rgb, hsv, lab, G, S, part, mode);
  if (mode)
    k1r_reduce<<<dim3(315), dim3(256), 0, stream>>>(part, G, S);
  else
    k1m_mirror<<<dim3(144, 4), dim3(256), 0, stream>>>(G);
  k2_small<<<dim3(8, 4), dim3(256), 0, stream>>>(G, S, Wq, bq, Wk, bk, Wv, bv, Mh, c0w);
  k3_out<<<dim3(256, 4), dim3(256), 0, stream>>>(rgb, hsv, lab, Mh, c0w, out);
}